// Round 21
// baseline (364.721 us; speedup 1.0000x reference)
//
#include <hip/hip_runtime.h>
#include <hip/hip_bf16.h>

// TokenRoutedMLP: N=32768 tokens, H=1024, 8 routed experts (id%8) + shared expert.
// Grouped bf16 MFMA GEMMs; shared expert folded via concat weights; gate/up
// interleaved by 16 cols in W1 so silu pairing is in-register.
// R21: k_gu widened to 128x256 tile (BK=32, 4 waves 2x2 of 64x128, 48 KB LDS,
// ~3 blk/CU) — 32 MFMA per wave-K-step amortize the 2 barriers (R20: 16).
// k_down stays R20-exact (128^2; N=1024 would give a bad grid tail at 256-wide).
// Epilogues transpose acc through LDS for coalesced stores; all acc indices
// compile-time static (rule #20 — R16's runtime index cost 7x).
// global_load_lds: LDS dest wave-uniform base + lane*16B (m104/m108).

#define N_TOK 32768
#define HD 1024
#define NE 8
#define MAXYT 264   // ceil((32768 + 8*127)/128)

typedef __attribute__((ext_vector_type(8))) short bf16x8;
typedef __attribute__((ext_vector_type(8))) unsigned short u16x8;
typedef __attribute__((ext_vector_type(4))) float f32x4;

__device__ __forceinline__ unsigned short f2bf(float f) {
  unsigned int x = __float_as_uint(f);
  x += 0x7fffu + ((x >> 16) & 1u);   // RTNE
  return (unsigned short)(x >> 16);
}

__device__ __forceinline__ void gld16(const unsigned short* g, unsigned short* l) {
  __builtin_amdgcn_global_load_lds(
      (const __attribute__((address_space(1))) unsigned int*)g,
      (__attribute__((address_space(3))) unsigned int*)l,
      16, 0, 0);
}

__device__ __forceinline__ int expert_of(int id) {
  int v = id < 0 ? 0 : (id > 99999 ? 99999 : id);
  return v & 7;
}

// ---------------- routing (LDS-histogram; 8 global atomics per block) ----------
__global__ void k_zero(int* ctrl) {
  if (threadIdx.x < 16) ctrl[threadIdx.x] = 0;   // cnt[8], cursor[8]
}

__global__ void k_count(const int* __restrict__ ids, int* __restrict__ cnt) {
  __shared__ int l[NE];
  if (threadIdx.x < NE) l[threadIdx.x] = 0;
  __syncthreads();
  int t = blockIdx.x * 256 + threadIdx.x;
  atomicAdd(&l[expert_of(ids[t])], 1);
  __syncthreads();
  if (threadIdx.x < NE) atomicAdd(&cnt[threadIdx.x], l[threadIdx.x]);
}

// off[0..8] = 128-aligned segment starts; off[9..17] = ybase (tile index starts)
__global__ void k_scan(const int* __restrict__ cnt, int* __restrict__ off) {
  if (threadIdx.x == 0 && blockIdx.x == 0) {
    int a = 0;
    for (int e = 0; e < NE; e++) { off[e] = a; a += (cnt[e] + 127) & ~127; }
    off[NE] = a;
    for (int e = 0; e <= NE; e++) off[9 + e] = off[e] >> 7;
  }
}

__global__ void k_fill(const int* __restrict__ ids, int* __restrict__ cursor,
                       const int* __restrict__ off, int* __restrict__ perm) {
  __shared__ int lcnt[NE], lbase[NE];
  if (threadIdx.x < NE) lcnt[threadIdx.x] = 0;
  __syncthreads();
  int t = blockIdx.x * 256 + threadIdx.x;
  int e = expert_of(ids[t]);
  int r = atomicAdd(&lcnt[e], 1);          // rank within block
  __syncthreads();
  if (threadIdx.x < NE)
    lbase[threadIdx.x] = atomicAdd(&cursor[threadIdx.x], lcnt[threadIdx.x]);
  __syncthreads();
  perm[off[e] + lbase[e] + r] = t;
}

// row remap: mode 0 plain; mode 1 gate-interleave; mode 2 up-interleave
__device__ __forceinline__ int rowmap(int c, int mode) {
  if (mode == 0) return c;
  return ((c >> 4) << 5) + (c & 15) + (mode == 2 ? 16 : 0);
}

// Fused prep: sections 0-5 = weight transpose/copy (4096 blocks each);
// blocks >= 24576: x f32 -> bf16 (16384 blocks, 8 elems/thread).
__global__ void k_prep(const float* __restrict__ gw, const float* __restrict__ uw,
                       const float* __restrict__ dw, const float* __restrict__ sgw,
                       const float* __restrict__ suw, const float* __restrict__ sdw,
                       const float* __restrict__ x,
                       unsigned short* __restrict__ W1, unsigned short* __restrict__ Dt,
                       unsigned short* __restrict__ xbf) {
  const int t = threadIdx.x;
  if (blockIdx.x >= 24576) {   // x conversion
    size_t i = ((size_t)(blockIdx.x - 24576) * 256 + t) * 8;
    float4 a = *reinterpret_cast<const float4*>(x + i);
    float4 b = *reinterpret_cast<const float4*>(x + i + 4);
    u16x8 o;
    o[0]=f2bf(a.x); o[1]=f2bf(a.y); o[2]=f2bf(a.z); o[3]=f2bf(a.w);
    o[4]=f2bf(b.x); o[5]=f2bf(b.y); o[6]=f2bf(b.z); o[7]=f2bf(b.w);
    *reinterpret_cast<u16x8*>(xbf + i) = o;
    return;
  }
  const int sec = blockIdx.x >> 12;
  const int idx = blockIdx.x & 4095;
  const int e = idx >> 9;
  __shared__ __attribute__((aligned(16))) float tile[32][33];
  if (sec < 3) {
    const float* src; unsigned short* dst; int C, mode, bx, by;
    size_t se, de;
    if (sec == 0)      { src = gw; dst = W1; C = 512;  mode = 1; se = (size_t)1024*512; de = (size_t)1<<21; bx = idx & 15; by = (idx >> 4) & 31; }
    else if (sec == 1) { src = uw; dst = W1; C = 512;  mode = 2; se = (size_t)1024*512; de = (size_t)1<<21; bx = idx & 15; by = (idx >> 4) & 31; }
    else               { src = dw; dst = Dt; C = 1024; mode = 0; se = (size_t)512*1024; de = (size_t)1<<20; bx = idx & 31; by = (idx >> 5) & 15; }
    src += e * se; dst += e * de;
    int r0 = by * 32, c0 = bx * 32;
    int row = t >> 3, c4 = (t & 7) * 4;
    float4 v = *reinterpret_cast<const float4*>(src + (size_t)(r0 + row) * C + c0 + c4);
    tile[row][c4+0] = v.x; tile[row][c4+1] = v.y; tile[row][c4+2] = v.z; tile[row][c4+3] = v.w;
    __syncthreads();
    ushort4 o;
    o.x = f2bf(tile[c4+0][row]); o.y = f2bf(tile[c4+1][row]);
    o.z = f2bf(tile[c4+2][row]); o.w = f2bf(tile[c4+3][row]);
    int orow = rowmap(c0 + row, mode);
    *reinterpret_cast<ushort4*>(dst + (size_t)orow * HD + r0 + c4) = o;
  } else {
    const float* src; unsigned short* dst; int mode, dcol, cols;
    size_t de;
    if (sec == 3)      { src = sgw; dst = W1; mode = 1; dcol = 0;   cols = 1024; de = (size_t)1<<21; }
    else if (sec == 4) { src = suw; dst = W1; mode = 2; dcol = 0;   cols = 1024; de = (size_t)1<<21; }
    else               { src = sdw; dst = Dt; mode = 0; dcol = 512; cols = 512;  de = (size_t)1<<20; }
    int bx = idx & 511;
    size_t i = ((size_t)bx * 256 + t) * 4;
    int r = (int)(i / cols), c = (int)(i % cols);
    int row = (mode == 0) ? r : (1024 + rowmap(r, mode));
    float4 v = *reinterpret_cast<const float4*>(src + i);
    ushort4 o; o.x=f2bf(v.x); o.y=f2bf(v.y); o.z=f2bf(v.z); o.w=f2bf(v.w);
    *reinterpret_cast<ushort4*>(dst + e * de + (size_t)row * HD + dcol + c) = o;
  }
}

// tile -> (expert, m0) from ybase table (off+9)
__device__ __forceinline__ int tile_expert(const int* yb, int yt) {
  int e = 0;
#pragma unroll
  for (int i = 1; i < NE; i++) if (yt >= yb[i]) e = i;
  return e;
}

// ---------------- GEMM 1: x @ W1(interleaved gate/up) + silu*mul -> inter ----------
// 256 thr = 4 waves (2x2, each 64x128). Tile M=128 tokens, N=256 W1-rows
// (=128 inter cols), BK=32. LDS: A 2x8KB + B 2x16KB = 48 KB (~3 blk/CU).
// Per wave-K-step: 32 MFMA, 12 ds_read_b128, 6 gld16, 2 barriers.
__global__ __launch_bounds__(256, 2) void k_gu(
    const unsigned short* __restrict__ xbf,
    const unsigned short* __restrict__ W1,   // [8][2048][1024]
    const int* __restrict__ perm, const int* __restrict__ cnt, const int* __restrict__ off,
    unsigned short* __restrict__ inter) {
  const int yt = blockIdx.y;
  const int e = tile_expert(off + 9, yt);
  const int ce = cnt[e];
  const int m0 = (yt - (off + 9)[e]) * 128;
  if (m0 >= ce) return;
  const int n0 = blockIdx.x * 256;
  const int oe = off[e];
  __shared__ __attribute__((aligned(16))) unsigned char smx[49152];
  unsigned short* smA = (unsigned short*)smx;            // 2 x 128x32 (16 KB)
  unsigned short* smB = (unsigned short*)(smx + 16384);  // 2 x 256x32 (32 KB)
  const int tid = threadIdx.x;
  const int lane = tid & 63;
  const int wv = tid >> 6;
  const int wm = wv >> 1, wn = wv & 1;

  const int srow = tid >> 2;            // 0..63
  const int skol = (tid & 3) * 8;
  const unsigned short* sa[2];
  const unsigned short* sb[4];
#pragma unroll
  for (int s = 0; s < 2; s++) {
    int i = m0 + s * 64 + srow;
    if (i > ce - 1) i = ce - 1;
    int tok = perm[oe + i];
    sa[s] = xbf + (size_t)tok * HD + skol;
  }
#pragma unroll
  for (int s = 0; s < 4; s++)
    sb[s] = W1 + ((size_t)e << 21) + (size_t)(n0 + s * 64 + srow) * HD + skol;

  f32x4 acc[4][8];
#pragma unroll
  for (int mi = 0; mi < 4; mi++)
#pragma unroll
    for (int ni = 0; ni < 8; ni++) acc[mi][ni] = (f32x4){0.f, 0.f, 0.f, 0.f};

  auto STAGE = [&](int b, int kt) {
    const int ko = kt * 32;
#pragma unroll
    for (int s = 0; s < 2; s++)
      gld16(sa[s] + ko, smA + b * 4096 + s * 2048 + wv * 512);   // wave-uniform dest
#pragma unroll
    for (int s = 0; s < 4; s++)
      gld16(sb[s] + ko, smB + b * 8192 + s * 2048 + wv * 512);
  };
  auto COMPUTE = [&](int b) {
    const unsigned short* A = smA + b * 4096;
    const unsigned short* B = smB + b * 8192;
    bf16x8 a[4], bb[8];
#pragma unroll
    for (int mi = 0; mi < 4; mi++)
      a[mi] = *reinterpret_cast<const bf16x8*>(A + (wm * 64 + mi * 16 + (lane & 15)) * 32 + (lane >> 4) * 8);
#pragma unroll
    for (int ni = 0; ni < 8; ni++)
      bb[ni] = *reinterpret_cast<const bf16x8*>(B + (wn * 128 + ni * 16 + (lane & 15)) * 32 + (lane >> 4) * 8);
#pragma unroll
    for (int mi = 0; mi < 4; mi++)
#pragma unroll
      for (int ni = 0; ni < 8; ni++)
        acc[mi][ni] = __builtin_amdgcn_mfma_f32_16x16x32_bf16(a[mi], bb[ni], acc[mi][ni], 0, 0, 0);
  };

  STAGE(0, 0);
  __syncthreads();
  int cur = 0;
#pragma unroll 1
  for (int kt = 0; kt < 31; kt++) {
    STAGE(cur ^ 1, kt + 1);   // next tile's loads fly during this tile's MFMA
    COMPUTE(cur);
    __syncthreads();          // drains vmcnt(0); other resident blocks hide it
    cur ^= 1;
  }
  COMPUTE(cur);

  // ---- coalesced epilogue: silu-pair -> LDS [128][128] ush -> short8 row stores
  // (all acc indices compile-time static — rule #20)
  __syncthreads();                      // all waves done with smA/smB
  unsigned short* xp = (unsigned short*)smx;   // [128][128], 32 KB
  const int q = lane >> 4, c = lane & 15;
#pragma unroll
  for (int mi = 0; mi < 4; mi++)
#pragma unroll
    for (int p = 0; p < 4; p++)
#pragma unroll
      for (int r = 0; r < 4; r++) {
        int lr = wm * 64 + mi * 16 + q * 4 + r;
        float g = acc[mi][2 * p][r];
        float u = acc[mi][2 * p + 1][r];
        float sv = g / (1.f + __expf(-g)) * u;
        xp[lr * 128 + wn * 64 + p * 16 + c] = f2bf(sv);
      }
  __syncthreads();
  const int colbase = n0 >> 1;          // block's 128 consecutive inter cols
#pragma unroll
  for (int j = 0; j < 8; j++) {
    int row = (tid >> 4) + j * 16;
    u16x8 v = *reinterpret_cast<const u16x8*>(xp + row * 128 + (tid & 15) * 8);
    *reinterpret_cast<u16x8*>(inter + (size_t)(oe + m0 + row) * HD + colbase + (tid & 15) * 8) = v;
  }
}

// ---------------- GEMM 2: inter @ Dcat -> out (scatter rows via perm) ----------------
// R20-exact. Tile M=128, N=128 out cols, BK=32, 32 KB LDS.
__global__ __launch_bounds__(256, 3) void k_down(
    const unsigned short* __restrict__ inter,
    const unsigned short* __restrict__ Dt,   // [8][1024][1024] B^T
    const int* __restrict__ perm, const int* __restrict__ cnt, const int* __restrict__ off,
    float* __restrict__ out) {
  const int yt = blockIdx.y;
  const int e = tile_expert(off + 9, yt);
  const int ce = cnt[e];
  const int m0 = (yt - (off + 9)[e]) * 128;
  if (m0 >= ce) return;
  const int n0 = blockIdx.x * 128;
  const int oe = off[e];
  __shared__ __attribute__((aligned(16))) unsigned char smx[32768];
  unsigned short* smA = (unsigned short*)smx;
  unsigned short* smB = (unsigned short*)(smx + 16384);
  const int tid = threadIdx.x;
  const int lane = tid & 63;
  const int wv = tid >> 6;
  const int wm = wv >> 1, wn = wv & 1;

  const int srow = tid >> 2;
  const int skol = (tid & 3) * 8;
  const unsigned short* sa[2];
  const unsigned short* sb[2];
#pragma unroll
  for (int s = 0; s < 2; s++) {
    sa[s] = inter + (size_t)(oe + m0 + s * 64 + srow) * HD + skol;
    sb[s] = Dt + ((size_t)e << 20) + (size_t)(n0 + s * 64 + srow) * HD + skol;
  }

  f32x4 acc[4][4];
#pragma unroll
  for (int mi = 0; mi < 4; mi++)
#pragma unroll
    for (int ni = 0; ni < 4; ni++) acc[mi][ni] = (f32x4){0.f, 0.f, 0.f, 0.f};

  auto STAGE = [&](int b, int kt) {
    const int ko = kt * 32;
#pragma unroll
    for (int s = 0; s < 2; s++) {
      gld16(sa[s] + ko, smA + b * 4096 + s * 2048 + wv * 512);
      gld16(sb[s] + ko, smB + b * 4096 + s * 2048 + wv * 512);
    }
  };
  auto COMPUTE = [&](int b) {
    const unsigned short* A = smA + b * 4096;
    const unsigned short* B = smB + b * 4096;
    bf16x8 a[4], bb[4];
#pragma unroll
    for (int mi = 0; mi < 4; mi++)
      a[mi] = *reinterpret_cast<const bf16x8*>(A + (wm * 64 + mi * 16 + (lane & 15)) * 32 + (lane >> 4) * 8);
#pragma unroll
    for (int ni = 0; ni < 4; ni++)
      bb[ni] = *reinterpret_cast<const bf16x8*>(B + (wn * 64 + ni * 16 + (lane & 15)) * 32 + (lane >> 4) * 8);
#pragma unroll
    for (int mi = 0; mi < 4; mi++)
#pragma unroll
      for (int ni = 0; ni < 4; ni++)
        acc[mi][ni] = __builtin_amdgcn_mfma_f32_16x16x32_bf16(a[mi], bb[ni], acc[mi][ni], 0, 0, 0);
  };

  STAGE(0, 0);
  __syncthreads();
  int cur = 0;
#pragma unroll 1
  for (int kt = 0; kt < 31; kt++) {
    STAGE(cur ^ 1, kt + 1);
    COMPUTE(cur);
    __syncthreads();
    cur ^= 1;
  }
  COMPUTE(cur);

  // ---- coalesced epilogue: TWO STATIC PASSES through LDS [128][64] f32 ----
  float* xp = (float*)smx;              // 32 KB = 128 x 64 f32
  const int q = lane >> 4, c = lane & 15;
#define DOWN_EPI(P)                                                           \
  do {                                                                        \
    __syncthreads();                                                          \
    _Pragma("unroll")                                                         \
    for (int mi = 0; mi < 4; mi++)                                            \
      _Pragma("unroll")                                                       \
      for (int j = 0; j < 2; j++)                                             \
        _Pragma("unroll")                                                     \
        for (int r = 0; r < 4; r++) {                                         \
          int lr = wm * 64 + mi * 16 + q * 4 + r;                             \
          xp[lr * 64 + wn * 32 + j * 16 + c] = acc[mi][2 * (P) + j][r];       \
        }                                                                     \
    __syncthreads();                                                          \
    _Pragma("unroll")                                                         \
    for (int j = 0; j < 8; j++) {                                             \
      int row = (tid >> 4) + j * 16;                                          \
      int gm = m0 + row;                                                      \
      if (gm < ce) {                                                          \
        int tk = perm[oe + gm];                                               \
        int lc = (tid & 15) * 4;                                              \
        float4 v = *reinterpret_cast<const float4*>(xp + row * 64 + lc);      \
        int gcol = n0 + (lc >> 5) * 64 + (P) * 32 + (lc & 31);                \
        *reinterpret_cast<float4*>(out + (size_t)tk * HD + gcol) = v;         \
      }                                                                       \
    }                                                                         \
  } while (0)
  DOWN_EPI(0);
  DOWN_EPI(1);
#undef DOWN_EPI
}

// ---------------- naive fp32 fallback (only if ws too small) ----------------
__global__ __launch_bounds__(256) void k_naive(
    const float* __restrict__ x, const int* __restrict__ ids,
    const float* __restrict__ gw, const float* __restrict__ uw, const float* __restrict__ dw,
    const float* __restrict__ sgw, const float* __restrict__ suw, const float* __restrict__ sdw,
    float* __restrict__ out) {
  const int t = blockIdx.x;
  const int tid = threadIdx.x;
  __shared__ float sx[1024];
  __shared__ float si[1024];
  for (int i = tid; i < 1024; i += 256) sx[i] = x[(size_t)t * 1024 + i];
  const int e = expert_of(ids[t]);
  __syncthreads();
  const float* gwe = gw + (size_t)e * 1024 * 512;
  const float* uwe = uw + (size_t)e * 1024 * 512;
  for (int j = tid; j < 512; j += 256) {
    float g = 0, u = 0, sg = 0, su = 0;
    for (int k = 0; k < 1024; k++) {
      float xv = sx[k];
      g += xv * gwe[(size_t)k * 512 + j];
      u += xv * uwe[(size_t)k * 512 + j];
      sg += xv * sgw[(size_t)j * 1024 + k];
      su += xv * suw[(size_t)j * 1024 + k];
    }
    si[j] = g / (1.f + __expf(-g)) * u;
    si[512 + j] = sg / (1.f + __expf(-sg)) * su;
  }
  __syncthreads();
  const float* dwe = dw + (size_t)e * 512 * 1024;
  for (int n = tid; n < 1024; n += 256) {
    float a = 0;
    for (int k = 0; k < 512; k++)
      a += si[k] * dwe[(size_t)k * 1024 + n] + si[512 + k] * sdw[(size_t)n * 512 + k];
    out[(size_t)t * 1024 + n] = a;
  }
}

extern "C" void kernel_launch(void* const* d_in, const int* in_sizes, int n_in,
                              void* d_out, int out_size, void* d_ws, size_t ws_size,
                              hipStream_t stream) {
  const float* x = (const float*)d_in[0];
  const int* ids = (const int*)d_in[1];          // harness passes integers as int32
  const float* gw = (const float*)d_in[2];
  const float* uw = (const float*)d_in[3];
  const float* dw = (const float*)d_in[4];
  const float* sgw = (const float*)d_in[5];
  const float* suw = (const float*)d_in[6];
  const float* sdw = (const float*)d_in[7];
  float* out = (float*)d_out;

  const size_t REQ = 186908672ull;
  if (ws_size < REQ) {
    k_naive<<<N_TOK, 256, 0, stream>>>(x, ids, gw, uw, dw, sgw, suw, sdw, out);
    return;
  }

  char* ws = (char*)d_ws;
  int* ctrl = (int*)ws;                                   // cnt[8]|cursor[8]|off[9]|ybase[9]
  int* perm = (int*)(ws + 1024);                          // 33792 ints
  unsigned short* xbf = (unsigned short*)(ws + 262144);   // [32768][1024]
  unsigned short* W1 = (unsigned short*)(ws + 67371008ull);   // [8][2048][1024] interleaved
  unsigned short* Dt = (unsigned short*)(ws + 100925440ull);  // [8][1024][1024]
  unsigned short* inter = (unsigned short*)(ws + 117702656ull); // [33792][1024]

  k_zero<<<1, 64, 0, stream>>>(ctrl);
  k_count<<<128, 256, 0, stream>>>(ids, ctrl);
  k_scan<<<1, 64, 0, stream>>>(ctrl, ctrl + 16);
  k_fill<<<128, 256, 0, stream>>>(ids, ctrl + 8, ctrl + 16, perm);
  k_prep<<<24576 + 16384, 256, 0, stream>>>(gw, uw, dw, sgw, suw, sdw, x, W1, Dt, xbf);
  // grouped GEMMs (compacted grid)
  k_gu<<<dim3(8, MAXYT), 256, 0, stream>>>(xbf, W1, perm, ctrl, ctrl + 16, inter);
  k_down<<<dim3(8, MAXYT), 256, 0, stream>>>(inter, Dt, perm, ctrl, ctrl + 16, out);
}

// Round 22
// 357.229 us; speedup vs baseline: 1.0210x; 1.0210x over previous
//
#include <hip/hip_runtime.h>
#include <hip/hip_bf16.h>

// TokenRoutedMLP: N=32768 tokens, H=1024, 8 routed experts (id%8) + shared expert.
// Grouped bf16 MFMA GEMMs; shared expert folded via concat weights; gate/up
// interleaved by 16 cols in W1 so silu pairing is in-register.
// GEMM loop: 2ph dbuf (128x128, BK=32, 4 waves, 32 KiB, ~3 blk/CU) — measured
// optimum of the 2-barrier family for this grouped K=1024 shape (R20: 358.5 us;
// 128x256 and 256^2 variants measured slower). Epilogues transpose acc through
// LDS for coalesced float4/short8 stores; all acc indices compile-time static
// (rule #20 — R16's runtime index demoted acc to scratch: 7x slowdown).
// global_load_lds: LDS dest wave-uniform base + lane*16B (m104/m108).

#define N_TOK 32768
#define HD 1024
#define NE 8
#define MAXYT 264   // ceil((32768 + 8*127)/128)

typedef __attribute__((ext_vector_type(8))) short bf16x8;
typedef __attribute__((ext_vector_type(8))) unsigned short u16x8;
typedef __attribute__((ext_vector_type(4))) float f32x4;

__device__ __forceinline__ unsigned short f2bf(float f) {
  unsigned int x = __float_as_uint(f);
  x += 0x7fffu + ((x >> 16) & 1u);   // RTNE
  return (unsigned short)(x >> 16);
}

__device__ __forceinline__ void gld16(const unsigned short* g, unsigned short* l) {
  __builtin_amdgcn_global_load_lds(
      (const __attribute__((address_space(1))) unsigned int*)g,
      (__attribute__((address_space(3))) unsigned int*)l,
      16, 0, 0);
}

__device__ __forceinline__ int expert_of(int id) {
  int v = id < 0 ? 0 : (id > 99999 ? 99999 : id);
  return v & 7;
}

// ---------------- routing (LDS-histogram; 8 global atomics per block) ----------
__global__ void k_zero(int* ctrl) {
  if (threadIdx.x < 16) ctrl[threadIdx.x] = 0;   // cnt[8], cursor[8]
}

__global__ void k_count(const int* __restrict__ ids, int* __restrict__ cnt) {
  __shared__ int l[NE];
  if (threadIdx.x < NE) l[threadIdx.x] = 0;
  __syncthreads();
  int t = blockIdx.x * 256 + threadIdx.x;
  atomicAdd(&l[expert_of(ids[t])], 1);
  __syncthreads();
  if (threadIdx.x < NE) atomicAdd(&cnt[threadIdx.x], l[threadIdx.x]);
}

// off[0..8] = 128-aligned segment starts; off[9..17] = ybase (tile index starts)
__global__ void k_scan(const int* __restrict__ cnt, int* __restrict__ off) {
  if (threadIdx.x == 0 && blockIdx.x == 0) {
    int a = 0;
    for (int e = 0; e < NE; e++) { off[e] = a; a += (cnt[e] + 127) & ~127; }
    off[NE] = a;
    for (int e = 0; e <= NE; e++) off[9 + e] = off[e] >> 7;
  }
}

__global__ void k_fill(const int* __restrict__ ids, int* __restrict__ cursor,
                       const int* __restrict__ off, int* __restrict__ perm) {
  __shared__ int lcnt[NE], lbase[NE];
  if (threadIdx.x < NE) lcnt[threadIdx.x] = 0;
  __syncthreads();
  int t = blockIdx.x * 256 + threadIdx.x;
  int e = expert_of(ids[t]);
  int r = atomicAdd(&lcnt[e], 1);          // rank within block
  __syncthreads();
  if (threadIdx.x < NE)
    lbase[threadIdx.x] = atomicAdd(&cursor[threadIdx.x], lcnt[threadIdx.x]);
  __syncthreads();
  perm[off[e] + lbase[e] + r] = t;
}

// row remap: mode 0 plain; mode 1 gate-interleave; mode 2 up-interleave
__device__ __forceinline__ int rowmap(int c, int mode) {
  if (mode == 0) return c;
  return ((c >> 4) << 5) + (c & 15) + (mode == 2 ? 16 : 0);
}

// Fused prep: sections 0-5 = weight transpose/copy (4096 blocks each);
// blocks >= 24576: x f32 -> bf16 (16384 blocks, 8 elems/thread).
__global__ void k_prep(const float* __restrict__ gw, const float* __restrict__ uw,
                       const float* __restrict__ dw, const float* __restrict__ sgw,
                       const float* __restrict__ suw, const float* __restrict__ sdw,
                       const float* __restrict__ x,
                       unsigned short* __restrict__ W1, unsigned short* __restrict__ Dt,
                       unsigned short* __restrict__ xbf) {
  const int t = threadIdx.x;
  if (blockIdx.x >= 24576) {   // x conversion
    size_t i = ((size_t)(blockIdx.x - 24576) * 256 + t) * 8;
    float4 a = *reinterpret_cast<const float4*>(x + i);
    float4 b = *reinterpret_cast<const float4*>(x + i + 4);
    u16x8 o;
    o[0]=f2bf(a.x); o[1]=f2bf(a.y); o[2]=f2bf(a.z); o[3]=f2bf(a.w);
    o[4]=f2bf(b.x); o[5]=f2bf(b.y); o[6]=f2bf(b.z); o[7]=f2bf(b.w);
    *reinterpret_cast<u16x8*>(xbf + i) = o;
    return;
  }
  const int sec = blockIdx.x >> 12;
  const int idx = blockIdx.x & 4095;
  const int e = idx >> 9;
  __shared__ __attribute__((aligned(16))) float tile[32][33];
  if (sec < 3) {
    const float* src; unsigned short* dst; int C, mode, bx, by;
    size_t se, de;
    if (sec == 0)      { src = gw; dst = W1; C = 512;  mode = 1; se = (size_t)1024*512; de = (size_t)1<<21; bx = idx & 15; by = (idx >> 4) & 31; }
    else if (sec == 1) { src = uw; dst = W1; C = 512;  mode = 2; se = (size_t)1024*512; de = (size_t)1<<21; bx = idx & 15; by = (idx >> 4) & 31; }
    else               { src = dw; dst = Dt; C = 1024; mode = 0; se = (size_t)512*1024; de = (size_t)1<<20; bx = idx & 31; by = (idx >> 5) & 15; }
    src += e * se; dst += e * de;
    int r0 = by * 32, c0 = bx * 32;
    int row = t >> 3, c4 = (t & 7) * 4;
    float4 v = *reinterpret_cast<const float4*>(src + (size_t)(r0 + row) * C + c0 + c4);
    tile[row][c4+0] = v.x; tile[row][c4+1] = v.y; tile[row][c4+2] = v.z; tile[row][c4+3] = v.w;
    __syncthreads();
    ushort4 o;
    o.x = f2bf(tile[c4+0][row]); o.y = f2bf(tile[c4+1][row]);
    o.z = f2bf(tile[c4+2][row]); o.w = f2bf(tile[c4+3][row]);
    int orow = rowmap(c0 + row, mode);
    *reinterpret_cast<ushort4*>(dst + (size_t)orow * HD + r0 + c4) = o;
  } else {
    const float* src; unsigned short* dst; int mode, dcol, cols;
    size_t de;
    if (sec == 3)      { src = sgw; dst = W1; mode = 1; dcol = 0;   cols = 1024; de = (size_t)1<<21; }
    else if (sec == 4) { src = suw; dst = W1; mode = 2; dcol = 0;   cols = 1024; de = (size_t)1<<21; }
    else               { src = sdw; dst = Dt; mode = 0; dcol = 512; cols = 512;  de = (size_t)1<<20; }
    int bx = idx & 511;
    size_t i = ((size_t)bx * 256 + t) * 4;
    int r = (int)(i / cols), c = (int)(i % cols);
    int row = (mode == 0) ? r : (1024 + rowmap(r, mode));
    float4 v = *reinterpret_cast<const float4*>(src + i);
    ushort4 o; o.x=f2bf(v.x); o.y=f2bf(v.y); o.z=f2bf(v.z); o.w=f2bf(v.w);
    *reinterpret_cast<ushort4*>(dst + e * de + (size_t)row * HD + dcol + c) = o;
  }
}

// tile -> (expert, m0) from ybase table (off+9)
__device__ __forceinline__ int tile_expert(const int* yb, int yt) {
  int e = 0;
#pragma unroll
  for (int i = 1; i < NE; i++) if (yt >= yb[i]) e = i;
  return e;
}

// ---------------- GEMM 1: x @ W1(interleaved gate/up) + silu*mul -> inter ----------
__global__ __launch_bounds__(256, 3) void k_gu(
    const unsigned short* __restrict__ xbf,
    const unsigned short* __restrict__ W1,   // [8][2048][1024]
    const int* __restrict__ perm, const int* __restrict__ cnt, const int* __restrict__ off,
    unsigned short* __restrict__ inter) {
  const int yt = blockIdx.y;
  const int e = tile_expert(off + 9, yt);
  const int ce = cnt[e];
  const int m0 = (yt - (off + 9)[e]) * 128;
  if (m0 >= ce) return;
  const int n0 = blockIdx.x * 128;
  const int oe = off[e];
  __shared__ __attribute__((aligned(16))) unsigned char smx[32768];
  unsigned short* smA = (unsigned short*)smx;          // 2 x 128 x 32 (16 KB)
  unsigned short* smB = (unsigned short*)(smx + 16384);
  const int tid = threadIdx.x;
  const int lane = tid & 63;
  const int wv = tid >> 6;
  const int wm = wv >> 1, wn = wv & 1;

  const int srow = tid >> 2;
  const int skol = (tid & 3) * 8;
  const unsigned short* sa[2];
  const unsigned short* sb[2];
#pragma unroll
  for (int s = 0; s < 2; s++) {
    int i = m0 + s * 64 + srow;
    if (i > ce - 1) i = ce - 1;
    int tok = perm[oe + i];
    sa[s] = xbf + (size_t)tok * HD + skol;
    sb[s] = W1 + ((size_t)e << 21) + (size_t)(n0 + s * 64 + srow) * HD + skol;
  }

  f32x4 acc[4][4];
#pragma unroll
  for (int mi = 0; mi < 4; mi++)
#pragma unroll
    for (int ni = 0; ni < 4; ni++) acc[mi][ni] = (f32x4){0.f, 0.f, 0.f, 0.f};

  auto STAGE = [&](int b, int kt) {
    const int ko = kt * 32;
#pragma unroll
    for (int s = 0; s < 2; s++) {
      gld16(sa[s] + ko, smA + b * 4096 + s * 2048 + wv * 512);  // wave-uniform dest
      gld16(sb[s] + ko, smB + b * 4096 + s * 2048 + wv * 512);
    }
  };
  auto COMPUTE = [&](int b) {
    const unsigned short* A = smA + b * 4096;
    const unsigned short* B = smB + b * 4096;
    bf16x8 a[4], bb[4];
#pragma unroll
    for (int mi = 0; mi < 4; mi++)
      a[mi] = *reinterpret_cast<const bf16x8*>(A + (wm * 64 + mi * 16 + (lane & 15)) * 32 + (lane >> 4) * 8);
#pragma unroll
    for (int ni = 0; ni < 4; ni++)
      bb[ni] = *reinterpret_cast<const bf16x8*>(B + (wn * 64 + ni * 16 + (lane & 15)) * 32 + (lane >> 4) * 8);
#pragma unroll
    for (int mi = 0; mi < 4; mi++)
#pragma unroll
      for (int ni = 0; ni < 4; ni++)
        acc[mi][ni] = __builtin_amdgcn_mfma_f32_16x16x32_bf16(a[mi], bb[ni], acc[mi][ni], 0, 0, 0);
  };

  STAGE(0, 0);
  __syncthreads();
  int cur = 0;
#pragma unroll 1
  for (int kt = 0; kt < 31; kt++) {
    STAGE(cur ^ 1, kt + 1);
    COMPUTE(cur);
    __syncthreads();
    cur ^= 1;
  }
  COMPUTE(cur);

  // ---- coalesced epilogue: silu-pair -> LDS [128][64] ush -> short8 row stores
  // (all acc indices compile-time static — rule #20)
  __syncthreads();                      // all waves done with smA/smB
  unsigned short* xp = (unsigned short*)smx;   // [128][64], stride 64
  const int q = lane >> 4, c = lane & 15;
#pragma unroll
  for (int mi = 0; mi < 4; mi++)
#pragma unroll
    for (int p = 0; p < 2; p++)
#pragma unroll
      for (int r = 0; r < 4; r++) {
        int lr = wm * 64 + mi * 16 + q * 4 + r;
        float g = acc[mi][2 * p][r];
        float u = acc[mi][2 * p + 1][r];
        float sv = g / (1.f + __expf(-g)) * u;
        xp[lr * 64 + wn * 32 + p * 16 + c] = f2bf(sv);
      }
  __syncthreads();
  const int colbase = n0 >> 1;          // block's 64 consecutive inter cols
#pragma unroll
  for (int j = 0; j < 4; j++) {
    int row = (tid >> 3) + j * 32;
    u16x8 v = *reinterpret_cast<const u16x8*>(xp + row * 64 + (tid & 7) * 8);
    *reinterpret_cast<u16x8*>(inter + (size_t)(oe + m0 + row) * HD + colbase + (tid & 7) * 8) = v;
  }
}

// ---------------- GEMM 2: inter @ Dcat -> out (scatter rows via perm) ----------------
__global__ __launch_bounds__(256, 3) void k_down(
    const unsigned short* __restrict__ inter,
    const unsigned short* __restrict__ Dt,   // [8][1024][1024] B^T
    const int* __restrict__ perm, const int* __restrict__ cnt, const int* __restrict__ off,
    float* __restrict__ out) {
  const int yt = blockIdx.y;
  const int e = tile_expert(off + 9, yt);
  const int ce = cnt[e];
  const int m0 = (yt - (off + 9)[e]) * 128;
  if (m0 >= ce) return;
  const int n0 = blockIdx.x * 128;
  const int oe = off[e];
  __shared__ __attribute__((aligned(16))) unsigned char smx[32768];
  unsigned short* smA = (unsigned short*)smx;
  unsigned short* smB = (unsigned short*)(smx + 16384);
  const int tid = threadIdx.x;
  const int lane = tid & 63;
  const int wv = tid >> 6;
  const int wm = wv >> 1, wn = wv & 1;

  const int srow = tid >> 2;
  const int skol = (tid & 3) * 8;
  const unsigned short* sa[2];
  const unsigned short* sb[2];
#pragma unroll
  for (int s = 0; s < 2; s++) {
    sa[s] = inter + (size_t)(oe + m0 + s * 64 + srow) * HD + skol;
    sb[s] = Dt + ((size_t)e << 20) + (size_t)(n0 + s * 64 + srow) * HD + skol;
  }

  f32x4 acc[4][4];
#pragma unroll
  for (int mi = 0; mi < 4; mi++)
#pragma unroll
    for (int ni = 0; ni < 4; ni++) acc[mi][ni] = (f32x4){0.f, 0.f, 0.f, 0.f};

  auto STAGE = [&](int b, int kt) {
    const int ko = kt * 32;
#pragma unroll
    for (int s = 0; s < 2; s++) {
      gld16(sa[s] + ko, smA + b * 4096 + s * 2048 + wv * 512);
      gld16(sb[s] + ko, smB + b * 4096 + s * 2048 + wv * 512);
    }
  };
  auto COMPUTE = [&](int b) {
    const unsigned short* A = smA + b * 4096;
    const unsigned short* B = smB + b * 4096;
    bf16x8 a[4], bb[4];
#pragma unroll
    for (int mi = 0; mi < 4; mi++)
      a[mi] = *reinterpret_cast<const bf16x8*>(A + (wm * 64 + mi * 16 + (lane & 15)) * 32 + (lane >> 4) * 8);
#pragma unroll
    for (int ni = 0; ni < 4; ni++)
      bb[ni] = *reinterpret_cast<const bf16x8*>(B + (wn * 64 + ni * 16 + (lane & 15)) * 32 + (lane >> 4) * 8);
#pragma unroll
    for (int mi = 0; mi < 4; mi++)
#pragma unroll
      for (int ni = 0; ni < 4; ni++)
        acc[mi][ni] = __builtin_amdgcn_mfma_f32_16x16x32_bf16(a[mi], bb[ni], acc[mi][ni], 0, 0, 0);
  };

  STAGE(0, 0);
  __syncthreads();
  int cur = 0;
#pragma unroll 1
  for (int kt = 0; kt < 31; kt++) {
    STAGE(cur ^ 1, kt + 1);
    COMPUTE(cur);
    __syncthreads();
    cur ^= 1;
  }
  COMPUTE(cur);

  // ---- coalesced epilogue: TWO STATIC PASSES through LDS [128][64] f32 ----
  // Rule #20: P must be a literal; runtime p demoted acc to scratch (R16).
  float* xp = (float*)smx;              // 32 KB = 128 x 64 f32
  const int q = lane >> 4, c = lane & 15;
#define DOWN_EPI(P)                                                           \
  do {                                                                        \
    __syncthreads();                                                          \
    _Pragma("unroll")                                                         \
    for (int mi = 0; mi < 4; mi++)                                            \
      _Pragma("unroll")                                                       \
      for (int j = 0; j < 2; j++)                                             \
        _Pragma("unroll")                                                     \
        for (int r = 0; r < 4; r++) {                                         \
          int lr = wm * 64 + mi * 16 + q * 4 + r;                             \
          xp[lr * 64 + wn * 32 + j * 16 + c] = acc[mi][2 * (P) + j][r];       \
        }                                                                     \
    __syncthreads();                                                          \
    _Pragma("unroll")                                                         \
    for (int j = 0; j < 8; j++) {                                             \
      int row = (tid >> 4) + j * 16;                                          \
      int gm = m0 + row;                                                      \
      if (gm < ce) {                                                          \
        int tk = perm[oe + gm];                                               \
        int lc = (tid & 15) * 4;                                              \
        float4 v = *reinterpret_cast<const float4*>(xp + row * 64 + lc);      \
        int gcol = n0 + (lc >> 5) * 64 + (P) * 32 + (lc & 31);                \
        *reinterpret_cast<float4*>(out + (size_t)tk * HD + gcol) = v;         \
      }                                                                       \
    }                                                                         \
  } while (0)
  DOWN_EPI(0);
  DOWN_EPI(1);
#undef DOWN_EPI
}

// ---------------- naive fp32 fallback (only if ws too small) ----------------
__global__ __launch_bounds__(256) void k_naive(
    const float* __restrict__ x, const int* __restrict__ ids,
    const float* __restrict__ gw, const float* __restrict__ uw, const float* __restrict__ dw,
    const float* __restrict__ sgw, const float* __restrict__ suw, const float* __restrict__ sdw,
    float* __restrict__ out) {
  const int t = blockIdx.x;
  const int tid = threadIdx.x;
  __shared__ float sx[1024];
  __shared__ float si[1024];
  for (int i = tid; i < 1024; i += 256) sx[i] = x[(size_t)t * 1024 + i];
  const int e = expert_of(ids[t]);
  __syncthreads();
  const float* gwe = gw + (size_t)e * 1024 * 512;
  const float* uwe = uw + (size_t)e * 1024 * 512;
  for (int j = tid; j < 512; j += 256) {
    float g = 0, u = 0, sg = 0, su = 0;
    for (int k = 0; k < 1024; k++) {
      float xv = sx[k];
      g += xv * gwe[(size_t)k * 512 + j];
      u += xv * uwe[(size_t)k * 512 + j];
      sg += xv * sgw[(size_t)j * 1024 + k];
      su += xv * suw[(size_t)j * 1024 + k];
    }
    si[j] = g / (1.f + __expf(-g)) * u;
    si[512 + j] = sg / (1.f + __expf(-sg)) * su;
  }
  __syncthreads();
  const float* dwe = dw + (size_t)e * 512 * 1024;
  for (int n = tid; n < 1024; n += 256) {
    float a = 0;
    for (int k = 0; k < 512; k++)
      a += si[k] * dwe[(size_t)k * 1024 + n] + si[512 + k] * sdw[(size_t)n * 512 + k];
    out[(size_t)t * 1024 + n] = a;
  }
}

extern "C" void kernel_launch(void* const* d_in, const int* in_sizes, int n_in,
                              void* d_out, int out_size, void* d_ws, size_t ws_size,
                              hipStream_t stream) {
  const float* x = (const float*)d_in[0];
  const int* ids = (const int*)d_in[1];          // harness passes integers as int32
  const float* gw = (const float*)d_in[2];
  const float* uw = (const float*)d_in[3];
  const float* dw = (const float*)d_in[4];
  const float* sgw = (const float*)d_in[5];
  const float* suw = (const float*)d_in[6];
  const float* sdw = (const float*)d_in[7];
  float* out = (float*)d_out;

  const size_t REQ = 186908672ull;
  if (ws_size < REQ) {
    k_naive<<<N_TOK, 256, 0, stream>>>(x, ids, gw, uw, dw, sgw, suw, sdw, out);
    return;
  }

  char* ws = (char*)d_ws;
  int* ctrl = (int*)ws;                                   // cnt[8]|cursor[8]|off[9]|ybase[9]
  int* perm = (int*)(ws + 1024);                          // 33792 ints
  unsigned short* xbf = (unsigned short*)(ws + 262144);   // [32768][1024]
  unsigned short* W1 = (unsigned short*)(ws + 67371008ull);   // [8][2048][1024] interleaved
  unsigned short* Dt = (unsigned short*)(ws + 100925440ull);  // [8][1024][1024]
  unsigned short* inter = (unsigned short*)(ws + 117702656ull); // [33792][1024]

  k_zero<<<1, 64, 0, stream>>>(ctrl);
  k_count<<<128, 256, 0, stream>>>(ids, ctrl);
  k_scan<<<1, 64, 0, stream>>>(ctrl, ctrl + 16);
  k_fill<<<128, 256, 0, stream>>>(ids, ctrl + 8, ctrl + 16, perm);
  k_prep<<<24576 + 16384, 256, 0, stream>>>(gw, uw, dw, sgw, suw, sdw, x, W1, Dt, xbf);
  // grouped GEMMs (128^2 tiles, compacted grid)
  k_gu<<<dim3(16, MAXYT), 256, 0, stream>>>(xbf, W1, perm, ctrl, ctrl + 16, inter);
  k_down<<<dim3(8, MAXYT), 256, 0, stream>>>(inter, Dt, perm, ctrl, ctrl + 16, out);
}

// Round 23
// 354.690 us; speedup vs baseline: 1.0283x; 1.0072x over previous
//
#include <hip/hip_runtime.h>
#include <hip/hip_bf16.h>

// TokenRoutedMLP: N=32768 tokens, H=1024, 8 routed experts (id%8) + shared expert.
// Grouped bf16 MFMA GEMMs; shared expert folded via concat weights; gate/up
// interleaved by 16 cols in W1 so silu pairing is in-register.
// GEMM loop: 2ph dbuf (128x128, BK=32, 4 waves, 32 KiB, ~3 blk/CU) — measured
// optimum of the 2-barrier family for this grouped K=1024 shape (R20/R22:
// 357-358 us). Epilogues transpose acc through LDS for coalesced stores; all
// acc indices compile-time static (rule #20).
// R23: routing-count folded into k_prep (per-block partial histograms, plain
// stores), k_zero eliminated, cursor zeroed in k_scan -> 5 launches (was 7).
// global_load_lds: LDS dest wave-uniform base + lane*16B (m104/m108).

#define N_TOK 32768
#define HD 1024
#define NE 8
#define MAXYT 264   // ceil((32768 + 8*127)/128)

typedef __attribute__((ext_vector_type(8))) short bf16x8;
typedef __attribute__((ext_vector_type(8))) unsigned short u16x8;
typedef __attribute__((ext_vector_type(4))) float f32x4;

__device__ __forceinline__ unsigned short f2bf(float f) {
  unsigned int x = __float_as_uint(f);
  x += 0x7fffu + ((x >> 16) & 1u);   // RTNE
  return (unsigned short)(x >> 16);
}

__device__ __forceinline__ void gld16(const unsigned short* g, unsigned short* l) {
  __builtin_amdgcn_global_load_lds(
      (const __attribute__((address_space(1))) unsigned int*)g,
      (__attribute__((address_space(3))) unsigned int*)l,
      16, 0, 0);
}

__device__ __forceinline__ int expert_of(int id) {
  int v = id < 0 ? 0 : (id > 99999 ? 99999 : id);
  return v & 7;
}

// row remap: mode 0 plain; mode 1 gate-interleave; mode 2 up-interleave
__device__ __forceinline__ int rowmap(int c, int mode) {
  if (mode == 0) return c;
  return ((c >> 4) << 5) + (c & 15) + (mode == 2 ? 16 : 0);
}

// Fused prep. Sections by blockIdx.x:
//   [0, 24576)        : weight transpose/copy (6 sections x 4096 blocks)
//   [24576, 40960)    : x f32 -> bf16 (16384 blocks, 8 elems/thread)
//   [40960, 41088)    : routing count -> per-block partial histograms (plain stores)
__global__ void k_prep(const float* __restrict__ gw, const float* __restrict__ uw,
                       const float* __restrict__ dw, const float* __restrict__ sgw,
                       const float* __restrict__ suw, const float* __restrict__ sdw,
                       const float* __restrict__ x, const int* __restrict__ ids,
                       unsigned short* __restrict__ W1, unsigned short* __restrict__ Dt,
                       unsigned short* __restrict__ xbf, int* __restrict__ cnt_part) {
  const int t = threadIdx.x;
  if (blockIdx.x >= 40960) {   // routing count
    __shared__ int l[NE];
    if (t < NE) l[t] = 0;
    __syncthreads();
    int tok = (blockIdx.x - 40960) * 256 + t;
    atomicAdd(&l[expert_of(ids[tok])], 1);
    __syncthreads();
    if (t < NE) cnt_part[(blockIdx.x - 40960) * NE + t] = l[t];
    return;
  }
  if (blockIdx.x >= 24576) {   // x conversion
    size_t i = ((size_t)(blockIdx.x - 24576) * 256 + t) * 8;
    float4 a = *reinterpret_cast<const float4*>(x + i);
    float4 b = *reinterpret_cast<const float4*>(x + i + 4);
    u16x8 o;
    o[0]=f2bf(a.x); o[1]=f2bf(a.y); o[2]=f2bf(a.z); o[3]=f2bf(a.w);
    o[4]=f2bf(b.x); o[5]=f2bf(b.y); o[6]=f2bf(b.z); o[7]=f2bf(b.w);
    *reinterpret_cast<u16x8*>(xbf + i) = o;
    return;
  }
  const int sec = blockIdx.x >> 12;
  const int idx = blockIdx.x & 4095;
  const int e = idx >> 9;
  __shared__ __attribute__((aligned(16))) float tile[32][33];
  if (sec < 3) {
    const float* src; unsigned short* dst; int C, mode, bx, by;
    size_t se, de;
    if (sec == 0)      { src = gw; dst = W1; C = 512;  mode = 1; se = (size_t)1024*512; de = (size_t)1<<21; bx = idx & 15; by = (idx >> 4) & 31; }
    else if (sec == 1) { src = uw; dst = W1; C = 512;  mode = 2; se = (size_t)1024*512; de = (size_t)1<<21; bx = idx & 15; by = (idx >> 4) & 31; }
    else               { src = dw; dst = Dt; C = 1024; mode = 0; se = (size_t)512*1024; de = (size_t)1<<20; bx = idx & 31; by = (idx >> 5) & 15; }
    src += e * se; dst += e * de;
    int r0 = by * 32, c0 = bx * 32;
    int row = t >> 3, c4 = (t & 7) * 4;
    float4 v = *reinterpret_cast<const float4*>(src + (size_t)(r0 + row) * C + c0 + c4);
    tile[row][c4+0] = v.x; tile[row][c4+1] = v.y; tile[row][c4+2] = v.z; tile[row][c4+3] = v.w;
    __syncthreads();
    ushort4 o;
    o.x = f2bf(tile[c4+0][row]); o.y = f2bf(tile[c4+1][row]);
    o.z = f2bf(tile[c4+2][row]); o.w = f2bf(tile[c4+3][row]);
    int orow = rowmap(c0 + row, mode);
    *reinterpret_cast<ushort4*>(dst + (size_t)orow * HD + r0 + c4) = o;
  } else {
    const float* src; unsigned short* dst; int mode, dcol, cols;
    size_t de;
    if (sec == 3)      { src = sgw; dst = W1; mode = 1; dcol = 0;   cols = 1024; de = (size_t)1<<21; }
    else if (sec == 4) { src = suw; dst = W1; mode = 2; dcol = 0;   cols = 1024; de = (size_t)1<<21; }
    else               { src = sdw; dst = Dt; mode = 0; dcol = 512; cols = 512;  de = (size_t)1<<20; }
    int bx = idx & 511;
    size_t i = ((size_t)bx * 256 + t) * 4;
    int r = (int)(i / cols), c = (int)(i % cols);
    int row = (mode == 0) ? r : (1024 + rowmap(r, mode));
    float4 v = *reinterpret_cast<const float4*>(src + i);
    ushort4 o; o.x=f2bf(v.x); o.y=f2bf(v.y); o.z=f2bf(v.z); o.w=f2bf(v.w);
    *reinterpret_cast<ushort4*>(dst + e * de + (size_t)row * HD + dcol + c) = o;
  }
}

// Sum partial histograms -> ctrl: cnt[0..8) cursor[8..16)=0 off[16..25) ybase[25..34)
__global__ void k_scan(const int* __restrict__ cnt_part, int* __restrict__ ctrl) {
  const int t = threadIdx.x;
  if (t < NE) {
    int s = 0;
#pragma unroll 4
    for (int b = 0; b < 128; b++) s += cnt_part[b * NE + t];
    ctrl[t] = s;        // cnt
    ctrl[8 + t] = 0;    // cursor (for k_fill)
  }
  __syncthreads();
  if (t == 0) {
    int a = 0;
    for (int e = 0; e < NE; e++) { ctrl[16 + e] = a; a += (ctrl[e] + 127) & ~127; }
    ctrl[16 + NE] = a;
    for (int e = 0; e <= NE; e++) ctrl[25 + e] = ctrl[16 + e] >> 7;
  }
}

__global__ void k_fill(const int* __restrict__ ids, int* __restrict__ cursor,
                       const int* __restrict__ off, int* __restrict__ perm) {
  __shared__ int lcnt[NE], lbase[NE];
  if (threadIdx.x < NE) lcnt[threadIdx.x] = 0;
  __syncthreads();
  int t = blockIdx.x * 256 + threadIdx.x;
  int e = expert_of(ids[t]);
  int r = atomicAdd(&lcnt[e], 1);          // rank within block
  __syncthreads();
  if (threadIdx.x < NE)
    lbase[threadIdx.x] = atomicAdd(&cursor[threadIdx.x], lcnt[threadIdx.x]);
  __syncthreads();
  perm[off[e] + lbase[e] + r] = t;
}

// tile -> (expert, m0) from ybase table (off+9)
__device__ __forceinline__ int tile_expert(const int* yb, int yt) {
  int e = 0;
#pragma unroll
  for (int i = 1; i < NE; i++) if (yt >= yb[i]) e = i;
  return e;
}

// ---------------- GEMM 1: x @ W1(interleaved gate/up) + silu*mul -> inter ----------
__global__ __launch_bounds__(256, 3) void k_gu(
    const unsigned short* __restrict__ xbf,
    const unsigned short* __restrict__ W1,   // [8][2048][1024]
    const int* __restrict__ perm, const int* __restrict__ cnt, const int* __restrict__ off,
    unsigned short* __restrict__ inter) {
  const int yt = blockIdx.y;
  const int e = tile_expert(off + 9, yt);
  const int ce = cnt[e];
  const int m0 = (yt - (off + 9)[e]) * 128;
  if (m0 >= ce) return;
  const int n0 = blockIdx.x * 128;
  const int oe = off[e];
  __shared__ __attribute__((aligned(16))) unsigned char smx[32768];
  unsigned short* smA = (unsigned short*)smx;          // 2 x 128 x 32 (16 KB)
  unsigned short* smB = (unsigned short*)(smx + 16384);
  const int tid = threadIdx.x;
  const int lane = tid & 63;
  const int wv = tid >> 6;
  const int wm = wv >> 1, wn = wv & 1;

  const int srow = tid >> 2;
  const int skol = (tid & 3) * 8;
  const unsigned short* sa[2];
  const unsigned short* sb[2];
#pragma unroll
  for (int s = 0; s < 2; s++) {
    int i = m0 + s * 64 + srow;
    if (i > ce - 1) i = ce - 1;
    int tok = perm[oe + i];
    sa[s] = xbf + (size_t)tok * HD + skol;
    sb[s] = W1 + ((size_t)e << 21) + (size_t)(n0 + s * 64 + srow) * HD + skol;
  }

  f32x4 acc[4][4];
#pragma unroll
  for (int mi = 0; mi < 4; mi++)
#pragma unroll
    for (int ni = 0; ni < 4; ni++) acc[mi][ni] = (f32x4){0.f, 0.f, 0.f, 0.f};

  auto STAGE = [&](int b, int kt) {
    const int ko = kt * 32;
#pragma unroll
    for (int s = 0; s < 2; s++) {
      gld16(sa[s] + ko, smA + b * 4096 + s * 2048 + wv * 512);  // wave-uniform dest
      gld16(sb[s] + ko, smB + b * 4096 + s * 2048 + wv * 512);
    }
  };
  auto COMPUTE = [&](int b) {
    const unsigned short* A = smA + b * 4096;
    const unsigned short* B = smB + b * 4096;
    bf16x8 a[4], bb[4];
#pragma unroll
    for (int mi = 0; mi < 4; mi++)
      a[mi] = *reinterpret_cast<const bf16x8*>(A + (wm * 64 + mi * 16 + (lane & 15)) * 32 + (lane >> 4) * 8);
#pragma unroll
    for (int ni = 0; ni < 4; ni++)
      bb[ni] = *reinterpret_cast<const bf16x8*>(B + (wn * 64 + ni * 16 + (lane & 15)) * 32 + (lane >> 4) * 8);
#pragma unroll
    for (int mi = 0; mi < 4; mi++)
#pragma unroll
      for (int ni = 0; ni < 4; ni++)
        acc[mi][ni] = __builtin_amdgcn_mfma_f32_16x16x32_bf16(a[mi], bb[ni], acc[mi][ni], 0, 0, 0);
  };

  STAGE(0, 0);
  __syncthreads();
  int cur = 0;
#pragma unroll 1
  for (int kt = 0; kt < 31; kt++) {
    STAGE(cur ^ 1, kt + 1);
    COMPUTE(cur);
    __syncthreads();
    cur ^= 1;
  }
  COMPUTE(cur);

  // ---- coalesced epilogue: silu-pair -> LDS [128][64] ush -> short8 row stores
  __syncthreads();                      // all waves done with smA/smB
  unsigned short* xp = (unsigned short*)smx;   // [128][64], stride 64
  const int q = lane >> 4, c = lane & 15;
#pragma unroll
  for (int mi = 0; mi < 4; mi++)
#pragma unroll
    for (int p = 0; p < 2; p++)
#pragma unroll
      for (int r = 0; r < 4; r++) {
        int lr = wm * 64 + mi * 16 + q * 4 + r;
        float g = acc[mi][2 * p][r];
        float u = acc[mi][2 * p + 1][r];
        float sv = g / (1.f + __expf(-g)) * u;
        xp[lr * 64 + wn * 32 + p * 16 + c] = f2bf(sv);
      }
  __syncthreads();
  const int colbase = n0 >> 1;          // block's 64 consecutive inter cols
#pragma unroll
  for (int j = 0; j < 4; j++) {
    int row = (tid >> 3) + j * 32;
    u16x8 v = *reinterpret_cast<const u16x8*>(xp + row * 64 + (tid & 7) * 8);
    *reinterpret_cast<u16x8*>(inter + (size_t)(oe + m0 + row) * HD + colbase + (tid & 7) * 8) = v;
  }
}

// ---------------- GEMM 2: inter @ Dcat -> out (scatter rows via perm) ----------------
__global__ __launch_bounds__(256, 3) void k_down(
    const unsigned short* __restrict__ inter,
    const unsigned short* __restrict__ Dt,   // [8][1024][1024] B^T
    const int* __restrict__ perm, const int* __restrict__ cnt, const int* __restrict__ off,
    float* __restrict__ out) {
  const int yt = blockIdx.y;
  const int e = tile_expert(off + 9, yt);
  const int ce = cnt[e];
  const int m0 = (yt - (off + 9)[e]) * 128;
  if (m0 >= ce) return;
  const int n0 = blockIdx.x * 128;
  const int oe = off[e];
  __shared__ __attribute__((aligned(16))) unsigned char smx[32768];
  unsigned short* smA = (unsigned short*)smx;
  unsigned short* smB = (unsigned short*)(smx + 16384);
  const int tid = threadIdx.x;
  const int lane = tid & 63;
  const int wv = tid >> 6;
  const int wm = wv >> 1, wn = wv & 1;

  const int srow = tid >> 2;
  const int skol = (tid & 3) * 8;
  const unsigned short* sa[2];
  const unsigned short* sb[2];
#pragma unroll
  for (int s = 0; s < 2; s++) {
    sa[s] = inter + (size_t)(oe + m0 + s * 64 + srow) * HD + skol;
    sb[s] = Dt + ((size_t)e << 20) + (size_t)(n0 + s * 64 + srow) * HD + skol;
  }

  f32x4 acc[4][4];
#pragma unroll
  for (int mi = 0; mi < 4; mi++)
#pragma unroll
    for (int ni = 0; ni < 4; ni++) acc[mi][ni] = (f32x4){0.f, 0.f, 0.f, 0.f};

  auto STAGE = [&](int b, int kt) {
    const int ko = kt * 32;
#pragma unroll
    for (int s = 0; s < 2; s++) {
      gld16(sa[s] + ko, smA + b * 4096 + s * 2048 + wv * 512);
      gld16(sb[s] + ko, smB + b * 4096 + s * 2048 + wv * 512);
    }
  };
  auto COMPUTE = [&](int b) {
    const unsigned short* A = smA + b * 4096;
    const unsigned short* B = smB + b * 4096;
    bf16x8 a[4], bb[4];
#pragma unroll
    for (int mi = 0; mi < 4; mi++)
      a[mi] = *reinterpret_cast<const bf16x8*>(A + (wm * 64 + mi * 16 + (lane & 15)) * 32 + (lane >> 4) * 8);
#pragma unroll
    for (int ni = 0; ni < 4; ni++)
      bb[ni] = *reinterpret_cast<const bf16x8*>(B + (wn * 64 + ni * 16 + (lane & 15)) * 32 + (lane >> 4) * 8);
#pragma unroll
    for (int mi = 0; mi < 4; mi++)
#pragma unroll
      for (int ni = 0; ni < 4; ni++)
        acc[mi][ni] = __builtin_amdgcn_mfma_f32_16x16x32_bf16(a[mi], bb[ni], acc[mi][ni], 0, 0, 0);
  };

  STAGE(0, 0);
  __syncthreads();
  int cur = 0;
#pragma unroll 1
  for (int kt = 0; kt < 31; kt++) {
    STAGE(cur ^ 1, kt + 1);
    COMPUTE(cur);
    __syncthreads();
    cur ^= 1;
  }
  COMPUTE(cur);

  // ---- coalesced epilogue: TWO STATIC PASSES through LDS [128][64] f32 ----
  // Rule #20: P must be a literal; runtime p demoted acc to scratch (R16).
  float* xp = (float*)smx;              // 32 KB = 128 x 64 f32
  const int q = lane >> 4, c = lane & 15;
#define DOWN_EPI(P)                                                           \
  do {                                                                        \
    __syncthreads();                                                          \
    _Pragma("unroll")                                                         \
    for (int mi = 0; mi < 4; mi++)                                            \
      _Pragma("unroll")                                                       \
      for (int j = 0; j < 2; j++)                                             \
        _Pragma("unroll")                                                     \
        for (int r = 0; r < 4; r++) {                                         \
          int lr = wm * 64 + mi * 16 + q * 4 + r;                             \
          xp[lr * 64 + wn * 32 + j * 16 + c] = acc[mi][2 * (P) + j][r];       \
        }                                                                     \
    __syncthreads();                                                          \
    _Pragma("unroll")                                                         \
    for (int j = 0; j < 8; j++) {                                             \
      int row = (tid >> 4) + j * 16;                                          \
      int gm = m0 + row;                                                      \
      if (gm < ce) {                                                          \
        int tk = perm[oe + gm];                                               \
        int lc = (tid & 15) * 4;                                              \
        float4 v = *reinterpret_cast<const float4*>(xp + row * 64 + lc);      \
        int gcol = n0 + (lc >> 5) * 64 + (P) * 32 + (lc & 31);                \
        *reinterpret_cast<float4*>(out + (size_t)tk * HD + gcol) = v;         \
      }                                                                       \
    }                                                                         \
  } while (0)
  DOWN_EPI(0);
  DOWN_EPI(1);
#undef DOWN_EPI
}

// ---------------- naive fp32 fallback (only if ws too small) ----------------
__global__ __launch_bounds__(256) void k_naive(
    const float* __restrict__ x, const int* __restrict__ ids,
    const float* __restrict__ gw, const float* __restrict__ uw, const float* __restrict__ dw,
    const float* __restrict__ sgw, const float* __restrict__ suw, const float* __restrict__ sdw,
    float* __restrict__ out) {
  const int t = blockIdx.x;
  const int tid = threadIdx.x;
  __shared__ float sx[1024];
  __shared__ float si[1024];
  for (int i = tid; i < 1024; i += 256) sx[i] = x[(size_t)t * 1024 + i];
  const int e = expert_of(ids[t]);
  __syncthreads();
  const float* gwe = gw + (size_t)e * 1024 * 512;
  const float* uwe = uw + (size_t)e * 1024 * 512;
  for (int j = tid; j < 512; j += 256) {
    float g = 0, u = 0, sg = 0, su = 0;
    for (int k = 0; k < 1024; k++) {
      float xv = sx[k];
      g += xv * gwe[(size_t)k * 512 + j];
      u += xv * uwe[(size_t)k * 512 + j];
      sg += xv * sgw[(size_t)j * 1024 + k];
      su += xv * suw[(size_t)j * 1024 + k];
    }
    si[j] = g / (1.f + __expf(-g)) * u;
    si[512 + j] = sg / (1.f + __expf(-sg)) * su;
  }
  __syncthreads();
  const float* dwe = dw + (size_t)e * 512 * 1024;
  for (int n = tid; n < 1024; n += 256) {
    float a = 0;
    for (int k = 0; k < 512; k++)
      a += si[k] * dwe[(size_t)k * 1024 + n] + si[512 + k] * sdw[(size_t)n * 512 + k];
    out[(size_t)t * 1024 + n] = a;
  }
}

extern "C" void kernel_launch(void* const* d_in, const int* in_sizes, int n_in,
                              void* d_out, int out_size, void* d_ws, size_t ws_size,
                              hipStream_t stream) {
  const float* x = (const float*)d_in[0];
  const int* ids = (const int*)d_in[1];          // harness passes integers as int32
  const float* gw = (const float*)d_in[2];
  const float* uw = (const float*)d_in[3];
  const float* dw = (const float*)d_in[4];
  const float* sgw = (const float*)d_in[5];
  const float* suw = (const float*)d_in[6];
  const float* sdw = (const float*)d_in[7];
  float* out = (float*)d_out;

  const size_t REQ = 186908672ull;
  if (ws_size < REQ) {
    k_naive<<<N_TOK, 256, 0, stream>>>(x, ids, gw, uw, dw, sgw, suw, sdw, out);
    return;
  }

  char* ws = (char*)d_ws;
  int* ctrl = (int*)ws;                                   // cnt[8]|cursor[8]|off[9]|ybase[9]
  int* perm = (int*)(ws + 1024);                          // 33792 ints
  int* cnt_part = (int*)(ws + 140288);                    // [128][8] partial histograms
  unsigned short* xbf = (unsigned short*)(ws + 262144);   // [32768][1024]
  unsigned short* W1 = (unsigned short*)(ws + 67371008ull);   // [8][2048][1024] interleaved
  unsigned short* Dt = (unsigned short*)(ws + 100925440ull);  // [8][1024][1024]
  unsigned short* inter = (unsigned short*)(ws + 117702656ull); // [33792][1024]

  // prep (weights + x-cvt + routing count), then scan, fill, GEMMs: 5 launches
  k_prep<<<41088, 256, 0, stream>>>(gw, uw, dw, sgw, suw, sdw, x, ids, W1, Dt, xbf, cnt_part);
  k_scan<<<1, 64, 0, stream>>>(cnt_part, ctrl);
  k_fill<<<128, 256, 0, stream>>>(ids, ctrl + 8, ctrl + 16, perm);
  k_gu<<<dim3(16, MAXYT), 256, 0, stream>>>(xbf, W1, perm, ctrl, ctrl + 16, inter);
  k_down<<<dim3(8, MAXYT), 256, 0, stream>>>(inter, Dt, perm, ctrl, ctrl + 16, out);
}